// Round 3
// baseline (3672.556 us; speedup 1.0000x reference)
//
#include <hip/hip_runtime.h>
#include <hip/hip_bf16.h>
#include <math.h>

// GCN forward: log_softmax(spmm(relu(spmm(x@W1)+b1) @ W2) + b2)
// Round 2: same as round 1 (dtype-agnostic via runtime detector) with the
// compile error fixed (out_ptr_cast removed). fp32 accumulation internally.

#define N_NODES 50000
#define NFEAT   512
#define NHID    128
#define NCLASS  40
#define NEDGE   1600000

__device__ __forceinline__ float ldf(const void* p, size_t i, int f32) {
    return f32 ? ((const float*)p)[i]
               : __bfloat162float(((const __hip_bfloat16*)p)[i]);
}

__global__ __launch_bounds__(256) void detect_kernel(
    const void* __restrict__ x, int* __restrict__ flag)
{
    __shared__ int bad;
    if (threadIdx.x == 0) bad = 0;
    __syncthreads();
    float v = __bfloat162float(((const __hip_bfloat16*)x)[threadIdx.x]);
    // catches NaN, inf, |v|>100 (x ~ N(0,1): impossible as bf16)
    if (!(v > -100.f && v < 100.f)) atomicAdd(&bad, 1);
    __syncthreads();
    if (threadIdx.x == 0) *flag = (bad >= 4) ? 1 : 0;   // 1 => fp32
}

__global__ __launch_bounds__(128) void gemm1_kernel(
    const void* __restrict__ x,
    const void* __restrict__ W1,
    float* __restrict__ XW,
    const int* __restrict__ flag)
{
    __shared__ float xs[NFEAT];
    const int f32 = *flag;
    const int row = blockIdx.x;
    const int j = threadIdx.x;
    for (int k = j; k < NFEAT; k += 128)
        xs[k] = ldf(x, (size_t)row * NFEAT + k, f32);
    __syncthreads();
    float acc = 0.f;
    #pragma unroll 8
    for (int k = 0; k < NFEAT; ++k)
        acc += xs[k] * ldf(W1, (size_t)k * NHID + j, f32);
    XW[(size_t)row * NHID + j] = acc;
}

__global__ __launch_bounds__(256) void spmm1_kernel(
    const int* __restrict__ esrc, const int* __restrict__ edst,
    const void* __restrict__ ev,
    const float* __restrict__ XW, float* __restrict__ H1,
    const int* __restrict__ flag)
{
    const int f32 = *flag;
    const int t = blockIdx.x * 256 + threadIdx.x;
    const int e = t >> 5;              // 32 lanes per edge, 4 feats each
    if (e >= NEDGE) return;
    const int f = (t & 31) * 4;
    const int src = esrc[e];
    const int dst = edst[e];
    const float v = ldf(ev, e, f32);
    const float4 xv = *(const float4*)(&XW[(size_t)src * NHID + f]);
    float* hp = &H1[(size_t)dst * NHID + f];
    atomicAdd(hp + 0, v * xv.x);
    atomicAdd(hp + 1, v * xv.y);
    atomicAdd(hp + 2, v * xv.z);
    atomicAdd(hp + 3, v * xv.w);
}

__global__ __launch_bounds__(64) void gemm2_kernel(
    const float* __restrict__ H1,
    const void* __restrict__ b1,
    const void* __restrict__ W2,
    float* __restrict__ HW,
    const int* __restrict__ flag)
{
    __shared__ float hs[NHID];
    const int f32 = *flag;
    const int row = blockIdx.x;
    const int tid = threadIdx.x;
    for (int k = tid; k < NHID; k += 64) {
        float hv = H1[(size_t)row * NHID + k] + ldf(b1, k, f32);
        hs[k] = hv > 0.f ? hv : 0.f;
    }
    __syncthreads();
    if (tid < NCLASS) {
        float acc = 0.f;
        #pragma unroll 8
        for (int k = 0; k < NHID; ++k)
            acc += hs[k] * ldf(W2, (size_t)k * NCLASS + tid, f32);
        HW[(size_t)row * NCLASS + tid] = acc;
    }
}

__global__ __launch_bounds__(256) void spmm2_kernel(
    const int* __restrict__ esrc, const int* __restrict__ edst,
    const void* __restrict__ ev,
    const float* __restrict__ HW, float* __restrict__ LG,
    const int* __restrict__ flag)
{
    const int f32 = *flag;
    const int e = blockIdx.x * 4 + (threadIdx.x >> 6);
    const int f = threadIdx.x & 63;
    if (e >= NEDGE || f >= NCLASS) return;
    const int src = esrc[e];
    const int dst = edst[e];
    const float v = ldf(ev, e, f32);
    atomicAdd(&LG[(size_t)dst * NCLASS + f], v * HW[(size_t)src * NCLASS + f]);
}

__global__ __launch_bounds__(256) void softmax_kernel(
    const float* __restrict__ LG,
    const void* __restrict__ b2,
    void* __restrict__ out,
    const int* __restrict__ flag)
{
    const int f32 = *flag;
    const int row = blockIdx.x * 4 + (threadIdx.x >> 6);
    const int f = threadIdx.x & 63;
    if (row >= N_NODES) return;
    float v = (f < NCLASS)
        ? LG[(size_t)row * NCLASS + f] + ldf(b2, f, f32)
        : -INFINITY;
    float m = v;
    #pragma unroll
    for (int o = 32; o >= 1; o >>= 1) m = fmaxf(m, __shfl_xor(m, o));
    float ex = (f < NCLASS) ? expf(v - m) : 0.f;
    float s = ex;
    #pragma unroll
    for (int o = 32; o >= 1; o >>= 1) s += __shfl_xor(s, o);
    if (f < NCLASS) {
        const float r = v - m - logf(s);
        const size_t idx = (size_t)row * NCLASS + f;
        if (f32) ((float*)out)[idx] = r;
        else     ((__hip_bfloat16*)out)[idx] = __float2bfloat16(r);
    }
}

extern "C" void kernel_launch(void* const* d_in, const int* in_sizes, int n_in,
                              void* d_out, int out_size, void* d_ws, size_t ws_size,
                              hipStream_t stream)
{
    const void* x   = d_in[0];
    const void* W1  = d_in[1];
    const void* b1  = d_in[2];
    const void* W2  = d_in[3];
    const void* b2  = d_in[4];
    const int* esrc = (const int*)d_in[5];
    const int* edst = (const int*)d_in[6];
    const void* ev  = d_in[7];

    float* XW = (float*)d_ws;                       // N*NHID
    float* H1 = XW + (size_t)N_NODES * NHID;        // N*NHID
    float* HW = H1 + (size_t)N_NODES * NHID;        // N*NCLASS
    float* LG = HW + (size_t)N_NODES * NCLASS;      // N*NCLASS
    int* FLAG = (int*)(LG + (size_t)N_NODES * NCLASS);

    (void)hipMemsetAsync(H1, 0, (size_t)N_NODES * NHID * sizeof(float), stream);
    (void)hipMemsetAsync(LG, 0, (size_t)N_NODES * NCLASS * sizeof(float), stream);

    detect_kernel<<<1, 256, 0, stream>>>(x, FLAG);

    gemm1_kernel<<<N_NODES, 128, 0, stream>>>(x, W1, XW, FLAG);

    const long long t1 = (long long)NEDGE * 32;
    spmm1_kernel<<<(int)((t1 + 255) / 256), 256, 0, stream>>>(esrc, edst, ev, XW, H1, FLAG);

    gemm2_kernel<<<N_NODES, 64, 0, stream>>>(H1, b1, W2, HW, FLAG);

    spmm2_kernel<<<(NEDGE + 3) / 4, 256, 0, stream>>>(esrc, edst, ev, HW, LG, FLAG);

    softmax_kernel<<<(N_NODES + 3) / 4, 256, 0, stream>>>(LG, b2, d_out, FLAG);
}

// Round 4
// 1268.207 us; speedup vs baseline: 2.8959x; 2.8959x over previous
//
#include <hip/hip_runtime.h>
#include <hip/hip_bf16.h>
#include <math.h>

// GCN forward: log_softmax(spmm(relu(spmm(x@W1)+b1) @ W2) + b2)
// Round 3: kill the scatter atomics. Per-launch counting-sort of edges by dst
// (count -> 1-block scan -> scatter), then both SPMMs are pull-mode gathers:
// one wave per destination row, fp32 register accumulation, no atomics.
// Fused: b1+ReLU into spmm1 epilogue; b2+log_softmax into spmm2 epilogue.
// Dtype-agnostic (runtime bf16/f32 detector) retained from round 2.

#define N_NODES 50000
#define NFEAT   512
#define NHID    128
#define NCLASS  40
#define NEDGE   1600000

__device__ __forceinline__ float ldf(const void* p, size_t i, int f32) {
    return f32 ? ((const float*)p)[i]
               : __bfloat162float(((const __hip_bfloat16*)p)[i]);
}

__global__ __launch_bounds__(256) void detect_kernel(
    const void* __restrict__ x, int* __restrict__ flag)
{
    __shared__ int bad;
    if (threadIdx.x == 0) bad = 0;
    __syncthreads();
    float v = __bfloat162float(((const __hip_bfloat16*)x)[threadIdx.x]);
    if (!(v > -100.f && v < 100.f)) atomicAdd(&bad, 1);
    __syncthreads();
    if (threadIdx.x == 0) *flag = (bad >= 4) ? 1 : 0;   // 1 => fp32
}

// ---- CSR build --------------------------------------------------------------

__global__ __launch_bounds__(256) void count_kernel(
    const int* __restrict__ edst, int* __restrict__ cnt)
{
    const int e = blockIdx.x * 256 + threadIdx.x;
    if (e < NEDGE) atomicAdd(&cnt[edst[e]], 1);
}

// single-block exclusive scan of 50000 counts -> row_ptr[50001] and wcur copy
__global__ __launch_bounds__(1024) void scan_kernel(
    const int* __restrict__ cnt, int* __restrict__ row_ptr,
    int* __restrict__ wcur)
{
    __shared__ int part[1024];
    const int t = threadIdx.x;
    const int CH = (N_NODES + 1023) / 1024;   // 49
    const int base = t * CH;
    int s = 0;
    for (int i = 0; i < CH; ++i) {
        int idx = base + i;
        if (idx < N_NODES) s += cnt[idx];
    }
    part[t] = s;
    __syncthreads();
    for (int off = 1; off < 1024; off <<= 1) {
        int v = (t >= off) ? part[t - off] : 0;
        __syncthreads();
        part[t] += v;
        __syncthreads();
    }
    int run = part[t] - s;                    // exclusive prefix for this chunk
    for (int i = 0; i < CH; ++i) {
        int idx = base + i;
        if (idx < N_NODES) {
            row_ptr[idx] = run;
            wcur[idx] = run;
            run += cnt[idx];
        }
    }
    if (t == 1023) row_ptr[N_NODES] = part[1023];
}

__global__ __launch_bounds__(256) void scatter_kernel(
    const int* __restrict__ esrc, const int* __restrict__ edst,
    const void* __restrict__ ev, int* __restrict__ wcur,
    int* __restrict__ src_s, float* __restrict__ val_s,
    const int* __restrict__ flag)
{
    const int f32 = *flag;
    const int e = blockIdx.x * 256 + threadIdx.x;
    if (e >= NEDGE) return;
    const int pos = atomicAdd(&wcur[edst[e]], 1);
    src_s[pos] = esrc[e];
    val_s[pos] = ldf(ev, e, f32);
}

// ---- dense + sparse compute -------------------------------------------------

__global__ __launch_bounds__(128) void gemm1_kernel(
    const void* __restrict__ x,
    const void* __restrict__ W1,
    float* __restrict__ XW,
    const int* __restrict__ flag)
{
    __shared__ float xs[NFEAT];
    const int f32 = *flag;
    const int row = blockIdx.x;
    const int j = threadIdx.x;
    for (int k = j; k < NFEAT; k += 128)
        xs[k] = ldf(x, (size_t)row * NFEAT + k, f32);
    __syncthreads();
    float acc = 0.f;
    #pragma unroll 8
    for (int k = 0; k < NFEAT; ++k)
        acc += xs[k] * ldf(W1, (size_t)k * NHID + j, f32);
    XW[(size_t)row * NHID + j] = acc;
}

// one wave per dst row; lane holds 2 feats (float2); fused +b1, ReLU
__global__ __launch_bounds__(256) void spmm1_gather_kernel(
    const int* __restrict__ row_ptr, const int* __restrict__ src_s,
    const float* __restrict__ val_s, const float* __restrict__ XW,
    const void* __restrict__ b1, float* __restrict__ H1,
    const int* __restrict__ flag)
{
    const int f32 = *flag;
    const int wave = threadIdx.x >> 6;
    const int lane = threadIdx.x & 63;
    const int row = blockIdx.x * 4 + wave;
    const int beg = row_ptr[row], end = row_ptr[row + 1];
    const float2* XW2 = (const float2*)XW;
    float2 acc = {0.f, 0.f};
    for (int j = beg; j < end; ++j) {
        const int s = src_s[j];
        const float v = val_s[j];
        const float2 xv = XW2[(size_t)s * 64 + lane];
        acc.x += v * xv.x;
        acc.y += v * xv.y;
    }
    acc.x = fmaxf(acc.x + ldf(b1, lane * 2 + 0, f32), 0.f);
    acc.y = fmaxf(acc.y + ldf(b1, lane * 2 + 1, f32), 0.f);
    ((float2*)H1)[(size_t)row * 64 + lane] = acc;
}

// 4 rows/block (wave per row): HW = H1 @ W2
__global__ __launch_bounds__(256) void gemm2_kernel(
    const float* __restrict__ H1,
    const void* __restrict__ W2,
    float* __restrict__ HW,
    const int* __restrict__ flag)
{
    __shared__ float hs[4][NHID];
    const int f32 = *flag;
    const int wave = threadIdx.x >> 6;
    const int lane = threadIdx.x & 63;
    const int row = blockIdx.x * 4 + wave;
    const float2 h = ((const float2*)H1)[(size_t)row * 64 + lane];
    hs[wave][lane * 2 + 0] = h.x;
    hs[wave][lane * 2 + 1] = h.y;
    __syncthreads();
    if (lane < NCLASS) {
        float acc = 0.f;
        #pragma unroll 8
        for (int k = 0; k < NHID; ++k)
            acc += hs[wave][k] * ldf(W2, (size_t)k * NCLASS + lane, f32);
        HW[(size_t)row * NCLASS + lane] = acc;
    }
}

// one wave per dst row; fused +b2 and log_softmax
__global__ __launch_bounds__(256) void spmm2_gather_kernel(
    const int* __restrict__ row_ptr, const int* __restrict__ src_s,
    const float* __restrict__ val_s, const float* __restrict__ HW,
    const void* __restrict__ b2, void* __restrict__ out,
    const int* __restrict__ flag)
{
    const int f32 = *flag;
    const int wave = threadIdx.x >> 6;
    const int lane = threadIdx.x & 63;
    const int row = blockIdx.x * 4 + wave;
    const int beg = row_ptr[row], end = row_ptr[row + 1];
    float acc = 0.f;
    for (int j = beg; j < end; ++j) {
        const int s = src_s[j];
        const float v = val_s[j];
        if (lane < NCLASS) acc += v * HW[(size_t)s * NCLASS + lane];
    }
    const float logit = (lane < NCLASS) ? acc + ldf(b2, lane, f32) : -INFINITY;
    float m = logit;
    #pragma unroll
    for (int o = 32; o >= 1; o >>= 1) m = fmaxf(m, __shfl_xor(m, o));
    float ex = (lane < NCLASS) ? expf(logit - m) : 0.f;
    float sm = ex;
    #pragma unroll
    for (int o = 32; o >= 1; o >>= 1) sm += __shfl_xor(sm, o);
    if (lane < NCLASS) {
        const float r = logit - m - logf(sm);
        const size_t idx = (size_t)row * NCLASS + lane;
        if (f32) ((float*)out)[idx] = r;
        else     ((__hip_bfloat16*)out)[idx] = __float2bfloat16(r);
    }
}

extern "C" void kernel_launch(void* const* d_in, const int* in_sizes, int n_in,
                              void* d_out, int out_size, void* d_ws, size_t ws_size,
                              hipStream_t stream)
{
    const void* x   = d_in[0];
    const void* W1  = d_in[1];
    const void* b1  = d_in[2];
    const void* W2  = d_in[3];
    const void* b2  = d_in[4];
    const int* esrc = (const int*)d_in[5];
    const int* edst = (const int*)d_in[6];
    const void* ev  = d_in[7];

    // workspace layout (floats/ints are both 4 B)
    float* XW      = (float*)d_ws;                         // N*NHID      (25.6 MB)
    float* H1      = XW + (size_t)N_NODES * NHID;          // N*NHID      (25.6 MB)
    float* HW      = H1 + (size_t)N_NODES * NHID;          // N*NCLASS    ( 8.0 MB)
    float* val_s   = HW + (size_t)N_NODES * NCLASS;        // NEDGE       ( 6.4 MB)
    int*   src_s   = (int*)(val_s + NEDGE);                // NEDGE       ( 6.4 MB)
    int*   cnt     = src_s + NEDGE;                        // N           ( 0.2 MB)
    int*   row_ptr = cnt + N_NODES;                        // N+1
    int*   wcur    = row_ptr + N_NODES + 1;                // N
    int*   FLAG    = wcur + N_NODES;                       // 1

    (void)hipMemsetAsync(cnt, 0, (size_t)N_NODES * sizeof(int), stream);

    detect_kernel<<<1, 256, 0, stream>>>(x, FLAG);

    count_kernel<<<NEDGE / 256, 256, 0, stream>>>(edst, cnt);
    scan_kernel<<<1, 1024, 0, stream>>>(cnt, row_ptr, wcur);
    scatter_kernel<<<NEDGE / 256, 256, 0, stream>>>(esrc, edst, ev, wcur,
                                                    src_s, val_s, FLAG);

    gemm1_kernel<<<N_NODES, 128, 0, stream>>>(x, W1, XW, FLAG);

    spmm1_gather_kernel<<<N_NODES / 4, 256, 0, stream>>>(row_ptr, src_s, val_s,
                                                         XW, b1, H1, FLAG);

    gemm2_kernel<<<N_NODES / 4, 256, 0, stream>>>(H1, W2, HW, FLAG);

    spmm2_gather_kernel<<<N_NODES / 4, 256, 0, stream>>>(row_ptr, src_s, val_s,
                                                         HW, b2, d_out, FLAG);
}